// Round 15
// baseline (360.505 us; speedup 1.0000x reference)
//
#include <hip/hip_runtime.h>
#include <hip/hip_bf16.h>
#include <math.h>

// ---------------- problem constants ----------------
#define P_N   300
#define C_N   512
#define H_F   50
#define W_F   67
#define HW_F  3350
#define D_N   1024
#define FIN   25088
#define NCLS  21
#define NCAND 6000
#define W_IMG 1072.0f
#define H_IMG 800.0f
#define BBOX_CLIP_F 4.135166556742356f
#define KS6   28
#define STEPS6_PER_Z 28
#define KS7   16
#define STEPS7_PER_Z 2
#define KSH   16
#define STEPSH_PER_Z 2
#define NHEAD 128
#define NW    96
#define A_SCALE 16.0f
#define B_SCALE 256.0f
#define O_SCALE (1.0f / 4096.0f)
#define TBLK  1680

typedef __attribute__((ext_vector_type(8)))  _Float16 half8;
typedef __attribute__((ext_vector_type(16))) float    f32x16;

__device__ __forceinline__ void splitA(float f, _Float16& h, _Float16& l) {
  float fs = f * A_SCALE;
  h = (_Float16)fs;
  l = (_Float16)(fs - (float)h);
}

__device__ __forceinline__ int swz(int slot, int ks) {
  return slot ^ ((slot >> 5) & 1) ^ (((slot >> 3) & 1) << 1) ^ ((ks & 1) << 2);
}

// half-index (within the 4096-half hi or lo half-blob) for the 8-half group (row, j8)
__device__ __forceinline__ int blob_half_idx(int row, int j8) {
  const int ksW = j8 >> 1, kc8 = j8 & 1;
  const int mf = row >> 5;
  return (mf * 2 + ksW) * 512 + swz((kc8 << 5) | (row & 31), ksW) * 8;
}

// ---------------- fused: feat transpose + head-weight padding + vcount zero ----------------
__global__ __launch_bounds__(256) void prep_transpose(const float* __restrict__ feat,
                                                      float* __restrict__ ft,
                                                      const float* __restrict__ cls_w,
                                                      const float* __restrict__ cls_b,
                                                      const float* __restrict__ reg_w,
                                                      const float* __restrict__ reg_b,
                                                      float* __restrict__ Wpad,
                                                      float* __restrict__ bpad,
                                                      int* __restrict__ vcount) {
  __shared__ float tile[32][33];
  const int bid = blockIdx.x;
  const int tid = threadIdx.x;
  if (bid < TBLK) {
    const int bx = bid % 105, byy = bid / 105;
    const int s0 = bx * 32, c0 = byy * 32;
    const int tx = tid & 31, ty = tid >> 5;
    for (int r = ty; r < 32; r += 8) {
      int c = c0 + r, s = s0 + tx;
      tile[r][tx] = (s < HW_F) ? feat[(size_t)c * HW_F + s] : 0.0f;
    }
    __syncthreads();
    for (int r = ty; r < 32; r += 8) {
      int s = s0 + r, c = c0 + tx;
      if (s < HW_F) ft[(size_t)s * C_N + c] = tile[tx][r];
    }
  } else {
    const int row = bid - TBLK;
    if (row == 0 && tid == 0) *vcount = 0;
    const float* src = (row < NCLS) ? (cls_w + (size_t)row * D_N)
                     : (row < 105)  ? (reg_w + (size_t)(row - NCLS) * D_N) : nullptr;
    float4 v = make_float4(0.f, 0.f, 0.f, 0.f);
    if (src) v = reinterpret_cast<const float4*>(src)[tid];
    reinterpret_cast<float4*>(Wpad + (size_t)row * D_N)[tid] = v;
    if (tid == 0)
      bpad[row] = (row < NCLS) ? cls_b[row] : (row < 105) ? reg_b[row - NCLS] : 0.0f;
  }
}

// ---------------- ROI align: block per (proposal, channel-half), branch-free inner loop ----------------
__global__ __launch_bounds__(256, 3) void roi_align_k(const float* __restrict__ ft,
                                                      const float* __restrict__ rois,
                                                      _Float16* __restrict__ Xhi,
                                                      _Float16* __restrict__ Xlo) {
  __shared__ _Float16 hbuf[12544] __attribute__((aligned(16)));
  __shared__ _Float16 lbuf[12544] __attribute__((aligned(16)));
  __shared__ float g_ly[14], g_hy[14], g_lx[14], g_hx[14];
  __shared__ int   g_yoL[14], g_yoH[14], g_xoL[14], g_xoH[14];

  const int p   = blockIdx.x;
  const int ch  = blockIdx.y;
  const int tid = threadIdx.x;

  if (tid < 14) {
    const float rx0 = rois[p*4+0], ry0 = rois[p*4+1], rx1 = rois[p*4+2], ry1 = rois[p*4+3];
    const float x0r = rx0 * 0.0625f - 0.5f;
    const float y0r = ry0 * 0.0625f - 0.5f;
    const float bw  = (rx1 - rx0) * 0.0625f * (1.0f / 7.0f);
    const float bh  = (ry1 - ry0) * 0.0625f * (1.0f / 7.0f);
    const float t   = ((float)tid + 0.5f) * 0.5f;

    const float ys = y0r + bh * t;
    const bool vy = (ys >= -1.0f) && (ys <= (float)H_F);
    float y = fminf(fmaxf(ys, 0.0f), (float)(H_F - 1));
    int yi = (int)floorf(y);
    const int yh = min(yi + 1, H_F - 1);
    float ly = y - (float)yi, hy = 1.0f - (y - (float)yi);
    if (!vy) { ly = 0.0f; hy = 0.0f; }
    g_ly[tid] = ly; g_hy[tid] = hy;
    g_yoL[tid] = yi * (W_F * C_N); g_yoH[tid] = yh * (W_F * C_N);

    const float xs = x0r + bw * t;
    const bool vx = (xs >= -1.0f) && (xs <= (float)W_F);
    float x = fminf(fmaxf(xs, 0.0f), (float)(W_F - 1));
    int xi = (int)floorf(x);
    const int xh = min(xi + 1, W_F - 1);
    float lx = x - (float)xi, hx = 1.0f - (x - (float)xi);
    if (!vx) { lx = 0.0f; hx = 0.0f; }
    g_lx[tid] = lx; g_hx[tid] = hx;
    g_xoL[tid] = xi * C_N; g_xoH[tid] = xh * C_N;
  }
  __syncthreads();

  const float* ftc = ft + ch * 256 + tid;
#pragma unroll 4
  for (int cell = 0; cell < 49; ++cell) {
    const int py = cell / 7;
    const int px = cell - py * 7;
    float acc = 0.0f;
#pragma unroll
    for (int sy = 0; sy < 2; ++sy) {
      const int iy = 2 * py + sy;
      const float ly = g_ly[iy], hy = g_hy[iy];
      const int yoL = g_yoL[iy], yoH = g_yoH[iy];
#pragma unroll
      for (int sx = 0; sx < 2; ++sx) {
        const int ix = 2 * px + sx;
        const float lx = g_lx[ix], hx = g_hx[ix];
        const int xoL = g_xoL[ix], xoH = g_xoH[ix];
        acc += (hy*hx)*ftc[yoL+xoL] + (hy*lx)*ftc[yoL+xoH]
             + (ly*hx)*ftc[yoH+xoL] + (ly*lx)*ftc[yoH+xoH];
      }
    }
    _Float16 h, l;
    splitA(acc * 0.25f, h, l);
    hbuf[tid * 49 + cell] = h;
    lbuf[tid * 49 + cell] = l;
  }
  __syncthreads();

  const size_t base = (size_t)p * FIN + (size_t)ch * 12544;
  const uint4* hs = (const uint4*)hbuf;
  const uint4* ls = (const uint4*)lbuf;
  uint4* dh = (uint4*)(Xhi + base);
  uint4* dl = (uint4*)(Xlo + base);
  for (int k = tid; k < 1568; k += 256) { dh[k] = hs[k]; dl[k] = ls[k]; }
}

// ---------------- reshuffle: linear hi/lo rows -> per-(tile,step) 16KB fragment blobs ----------------
__global__ __launch_bounds__(256) void reshuffle_x(const _Float16* __restrict__ Shi,
                                                   const _Float16* __restrict__ Slo,
                                                   char* __restrict__ blob,
                                                   int M2, int K) {
  __shared__ _Float16 buf[8192] __attribute__((aligned(16)));
  const int tile = blockIdx.x, step = blockIdx.y;
  const int tid = threadIdx.x;
  const int steps = K >> 5;
#pragma unroll
  for (int i = 0; i < 4; ++i) {
    const int g = tid + i * 256;            // 0..1023
    const int half = g >> 9;                // 0: hi, 1: lo
    const int row = (g >> 2) & 127;
    const int j8 = g & 3;
    const int gm = tile * 128 + row;
    uint4 v = make_uint4(0, 0, 0, 0);
    if (gm < M2) {
      const _Float16* src = (half ? Slo : Shi) + (size_t)gm * K + (step << 5) + (j8 << 3);
      v = *reinterpret_cast<const uint4*>(src);
    }
    *reinterpret_cast<uint4*>(buf + half * 4096 + blob_half_idx(row, j8)) = v;
  }
  __syncthreads();
  uint4* dst = (uint4*)(blob + (((size_t)tile * steps + step) << 14));
  const uint4* s = (const uint4*)buf;
#pragma unroll
  for (int i = 0; i < 4; ++i) dst[tid + i * 256] = s[tid + i * 256];
}

// ---------------- MFMA f16 3-product GEMM: R11 geometry + T3 2-phase (dbuf, stage-before-compute) ----
__global__ __launch_bounds__(256, 2) void gemm_f16_3p(
    const char* __restrict__ Ablob, const float* __restrict__ Wt, float* __restrict__ Pt,
    int M, int K, int steps_per_z, int ldc)
{
  __shared__ _Float16 lds[32768] __attribute__((aligned(16)));   // 2 x 32KB buffers
  const int tid  = threadIdx.x;
  const int lane = tid & 63, wave = tid >> 6;
  const int wm = wave >> 1, wn = wave & 1;

  // XCD-aware bijective swizzle (grid divisible by 8)
  const int GX = gridDim.x, GY = gridDim.y;
  const int T  = GX * GY * gridDim.z;
  int flat = blockIdx.x + GX * (blockIdx.y + GY * blockIdx.z);
  if ((T & 7) == 0) flat = (flat & 7) * (T >> 3) + (flat >> 3);
  const int bx = flat % GX;
  const int by = (flat / GX) % GY;
  const int bz = flat / (GX * GY);

  const int m0 = bx * 128, n0 = by * 128;
  const int steps_total = K >> 5;
  const int s0 = bz * steps_per_z;
  const int s1 = min(s0 + steps_per_z, steps_total);

  f32x16 acc[2][2];
#pragma unroll
  for (int a = 0; a < 2; ++a)
#pragma unroll
    for (int b = 0; b < 2; ++b)
#pragma unroll
      for (int r = 0; r < 16; ++r) acc[a][b][r] = 0.f;

  const int srow = tid >> 2;
  const int j8   = tid & 3;
  const int ksW  = j8 >> 1, kc8 = j8 & 1;
  const int wslot = swz((kc8 << 5) | (srow & 31), ksW);

  auto stage = [&](int buf, int step) {
    // A: 4 async global_load_lds per wave (16KB blob -> this buffer's A region)
    const char* Ab = Ablob + (((size_t)bx * steps_total + step) << 14);
    char* ldsb = (char*)lds + (buf << 15);
#pragma unroll
    for (int c2 = 0; c2 < 4; ++c2) {
      const int off = ((wave << 2) + c2) << 10;
      __builtin_amdgcn_global_load_lds(
          (const __attribute__((address_space(1))) uint32_t*)(Ab + off + (lane << 4)),
          (__attribute__((address_space(3))) uint32_t*)(ldsb + off),
          16, 0, 0);
    }
    // B: convert f32 W -> f16 hi/lo, 2 row-chunks per thread
    _Float16* ldsh = (_Float16*)ldsb;
    const int kb = step << 5;
#pragma unroll
    for (int half = 0; half < 2; ++half) {
      const int n = srow + half * 64;
      const float* wp = Wt + (size_t)(n0 + n) * K + kb + j8 * 8;
      const float4 f0 = *reinterpret_cast<const float4*>(wp);
      const float4 f1 = *reinterpret_cast<const float4*>(wp + 4);
      float fv[8] = {f0.x, f0.y, f0.z, f0.w, f1.x, f1.y, f1.z, f1.w};
      union { _Float16 h[8]; uint4 v; } uh, ul;
#pragma unroll
      for (int e = 0; e < 8; ++e) {
        float fs = fv[e] * B_SCALE;
        uh.h[e] = (_Float16)fs;
        ul.h[e] = (_Float16)(fs - (float)uh.h[e]);
      }
      const int nf = n >> 5;
      const int base = 8192 + (nf * 2 + ksW) * 512 + wslot * 8;
      *reinterpret_cast<uint4*>(&ldsh[base])        = uh.v;
      *reinterpret_cast<uint4*>(&ldsh[4096 + base]) = ul.v;
    }
  };

  auto compute = [&](int buf) {
    _Float16* ldsh = (_Float16*)((char*)lds + (buf << 15));
#pragma unroll
    for (int ks = 0; ks < 2; ++ks) {
      const int rslot = swz(lane, ks) * 8;
      half8 ah[2], al[2], bh[2], bl[2];
#pragma unroll
      for (int mi = 0; mi < 2; ++mi) {
        const int mf = wm * 2 + mi;
        ah[mi] = *reinterpret_cast<const half8*>(&ldsh[(mf * 2 + ks) * 512 + rslot]);
        al[mi] = *reinterpret_cast<const half8*>(&ldsh[4096 + (mf * 2 + ks) * 512 + rslot]);
      }
#pragma unroll
      for (int ni = 0; ni < 2; ++ni) {
        const int nf = wn * 2 + ni;
        bh[ni] = *reinterpret_cast<const half8*>(&ldsh[8192  + (nf * 2 + ks) * 512 + rslot]);
        bl[ni] = *reinterpret_cast<const half8*>(&ldsh[12288 + (nf * 2 + ks) * 512 + rslot]);
      }
#pragma unroll
      for (int mi = 0; mi < 2; ++mi)
#pragma unroll
        for (int ni = 0; ni < 2; ++ni) {
          acc[mi][ni] = __builtin_amdgcn_mfma_f32_32x32x16_f16(ah[mi], bh[ni], acc[mi][ni], 0, 0, 0);
          acc[mi][ni] = __builtin_amdgcn_mfma_f32_32x32x16_f16(ah[mi], bl[ni], acc[mi][ni], 0, 0, 0);
          acc[mi][ni] = __builtin_amdgcn_mfma_f32_32x32x16_f16(al[mi], bh[ni], acc[mi][ni], 0, 0, 0);
        }
    }
  };

  // T3 2-phase: prologue stage, then {stage(next) BEFORE compute(cur); one barrier/step}
  if (s0 < s1) stage(0, s0);
  __syncthreads();
  int cur = 0;
  for (int s = s0; s < s1; ++s) {
    if (s + 1 < s1) stage(cur ^ 1, s + 1);
    __builtin_amdgcn_s_setprio(1);
    compute(cur);
    __builtin_amdgcn_s_setprio(0);
    __syncthreads();
    cur ^= 1;
  }

  const int col = lane & 31, rhi = lane >> 5;
  float* outp = Pt + (size_t)bz * ((size_t)M * ldc);
#pragma unroll
  for (int mi = 0; mi < 2; ++mi)
#pragma unroll
    for (int ni = 0; ni < 2; ++ni) {
      const int n = n0 + (wn * 2 + ni) * 32 + col;
      if (n >= ldc) continue;
#pragma unroll
      for (int r = 0; r < 16; ++r) {
        const int m = m0 + (wm * 2 + mi) * 32 + ((r & 3) + 8 * (r >> 2) + 4 * rhi);
        if (m < M) outp[(size_t)m * ldc + n] = acc[mi][ni][r] * O_SCALE;
      }
    }
}

// ---------------- reduce split-K + bias + relu -> fragment blob (hi/lo), D=1024 ----------------
__global__ __launch_bounds__(256) void reduce_frag(const float* __restrict__ Pt,
                                                   const float* __restrict__ bias,
                                                   char* __restrict__ blob,
                                                   int KS, int stepsB) {
  const int g = blockIdx.x * 256 + threadIdx.x;
  if (g >= P_N * 128) return;
  const int m = g >> 7;
  const int gg = g & 127;
  const int n0 = gg << 3;
  float s[8];
#pragma unroll
  for (int e = 0; e < 8; ++e) s[e] = bias[n0 + e];
  for (int k2 = 0; k2 < KS; ++k2) {
    const float* pp = Pt + ((size_t)k2 * P_N + m) * D_N + n0;
    const float4 a = *reinterpret_cast<const float4*>(pp);
    const float4 b = *reinterpret_cast<const float4*>(pp + 4);
    s[0]+=a.x; s[1]+=a.y; s[2]+=a.z; s[3]+=a.w;
    s[4]+=b.x; s[5]+=b.y; s[6]+=b.z; s[7]+=b.w;
  }
  union { _Float16 h[8]; uint4 v; } uh, ul;
#pragma unroll
  for (int e = 0; e < 8; ++e) {
    float r = fmaxf(s[e], 0.0f);
    _Float16 h, l; splitA(r, h, l);
    uh.h[e] = h; ul.h[e] = l;
  }
  const int tile = m >> 7, row = m & 127;
  const int step = gg >> 2, j8 = gg & 3;
  _Float16* dst = (_Float16*)(blob + (((size_t)tile * stepsB + step) << 14));
  const int hidx = blob_half_idx(row, j8);
  *reinterpret_cast<uint4*>(dst + hidx) = uh.v;
  *reinterpret_cast<uint4*>(dst + 4096 + hidx) = ul.v;
}

// ---------------- decode (fused logits-reduce): softmax + box decode + validity + compact ----------
__global__ __launch_bounds__(64) void decode_kernel(const float* __restrict__ Pt,
                                                    const float* __restrict__ bpad,
                                                    const float* __restrict__ props,
                                                    float* __restrict__ cboxes,
                                                    unsigned long long* __restrict__ ckeys,
                                                    int* __restrict__ vcount) {
  const int p = blockIdx.x;
  const int lane = threadIdx.x;
  __shared__ float lg[NHEAD];

  for (int o = lane; o < NHEAD; o += 64) {
    float s = 0.0f;
    for (int k = 0; k < KSH; ++k)
      s += Pt[((size_t)k * P_N + p) * NHEAD + o];
    lg[o] = s + bpad[o];
  }
  __syncthreads();

  float s = (lane < NCLS) ? lg[lane] : -__builtin_inff();
  float mx = s;
#pragma unroll
  for (int off = 32; off > 0; off >>= 1) mx = fmaxf(mx, __shfl_xor(mx, off));
  float e = (lane < NCLS) ? expf(s - mx) : 0.0f;
  float sum = e;
#pragma unroll
  for (int off = 32; off > 0; off >>= 1) sum += __shfl_xor(sum, off);
  const float sm = e / sum;

  if (lane >= 1 && lane < NCLS) {
    const int c = lane;
    const float x0 = props[p*4+0], y0 = props[p*4+1], x1 = props[p*4+2], y1 = props[p*4+3];
    const float w = x1 - x0, hh = y1 - y0;
    const float cx = x0 + 0.5f * w, cy = y0 + 0.5f * hh;
    const float dx = lg[NCLS + c*4 + 0];
    const float dy = lg[NCLS + c*4 + 1];
    const float dw = fminf(lg[NCLS + c*4 + 2], BBOX_CLIP_F);
    const float dh = fminf(lg[NCLS + c*4 + 3], BBOX_CLIP_F);
    const float pcx = dx * w + cx, pcy = dy * hh + cy;
    const float pw = expf(dw) * w, ph = expf(dh) * hh;
    float bx0 = pcx - 0.5f * pw, by0 = pcy - 0.5f * ph;
    float bx1 = pcx + 0.5f * pw, by1 = pcy + 0.5f * ph;
    bx0 = fminf(fmaxf(bx0, 0.0f), W_IMG);
    by0 = fminf(fmaxf(by0, 0.0f), H_IMG);
    bx1 = fminf(fmaxf(bx1, 0.0f), W_IMG);
    by1 = fminf(fmaxf(by1, 0.0f), H_IMG);
    const int idx = p * 20 + (c - 1);
    cboxes[idx*4+0] = bx0; cboxes[idx*4+1] = by0;
    cboxes[idx*4+2] = bx1; cboxes[idx*4+3] = by1;
    const bool valid = (sm > 0.05f) && ((bx1 - bx0) >= 1.0f) && ((by1 - by0) >= 1.0f);
    if (valid) {
      int pos = atomicAdd(vcount, 1);
      unsigned u = __float_as_uint(sm);
      ckeys[pos] = ((unsigned long long)(~u) << 32) | (unsigned)idx;
    }
  }
}

// ---------------- bitonic sort + gather ----------------
__global__ __launch_bounds__(1024) void sort_gather(const unsigned long long* __restrict__ ckeys,
                                                    const int* __restrict__ vcount,
                                                    const float* __restrict__ cboxes,
                                                    float4* __restrict__ sbox,
                                                    float* __restrict__ sscore,
                                                    int* __restrict__ slab) {
  __shared__ unsigned long long keys[8192];
  const int tid = threadIdx.x;
  const int V = *vcount;
  int Npad = 64; while (Npad < V) Npad <<= 1;
  for (int i = tid; i < Npad; i += 1024)
    keys[i] = (i < V) ? ckeys[i] : ~0ULL;
  __syncthreads();
  for (int kk = 2; kk <= Npad; kk <<= 1) {
    for (int j = kk >> 1; j > 0; j >>= 1) {
      for (int i = tid; i < Npad; i += 1024) {
        int ij = i ^ j;
        if (ij > i) {
          unsigned long long a = keys[i], b = keys[ij];
          bool up = ((i & kk) == 0);
          if ((a > b) == up) { keys[i] = b; keys[ij] = a; }
        }
      }
      __syncthreads();
    }
  }
  for (int i = tid; i < V; i += 1024) {
    unsigned long long key = keys[i];
    int idx = (int)(key & 0xffffffffu);
    sbox[i]   = *reinterpret_cast<const float4*>(&cboxes[(size_t)idx * 4]);
    sscore[i] = __uint_as_float(~(unsigned)(key >> 32));
    slab[i]   = idx % 20;
  }
}

// ---------------- suppression matrix ----------------
__global__ __launch_bounds__(256) void iou_matrix(const float4* __restrict__ sbox,
                                                  const int* __restrict__ slab,
                                                  const int* __restrict__ vcount,
                                                  unsigned long long* __restrict__ mask) {
  const int V = *vcount;
  const int i = blockIdx.x * 4 + (threadIdx.x >> 6);
  const int lane = threadIdx.x & 63;
  if (i >= V) return;
  const float4 bi = sbox[i];
  const int li = slab[i];
  const float ai = (bi.z - bi.x) * (bi.w - bi.y);
  const int nw = (V + 63) >> 6;
  for (int w = 0; w < nw; ++w) {
    const int j = (w << 6) + lane;
    bool sup = false;
    if (j > i && j < V && slab[j] == li) {
      const float4 bj = sbox[j];
      const float iw = fminf(bi.z, bj.z) - fmaxf(bi.x, bj.x);
      const float ih = fminf(bi.w, bj.w) - fmaxf(bi.y, bj.y);
      const float inter = fmaxf(iw, 0.0f) * fmaxf(ih, 0.0f);
      const float aj = (bj.z - bj.x) * (bj.w - bj.y);
      sup = inter / (ai + aj - inter) > 0.5f;
    }
    const unsigned long long m = __ballot(sup);
    if (lane == 0) mask[(size_t)i * NW + w] = m;
  }
}

// ---------------- NMS scan ----------------
__device__ __forceinline__ unsigned long long bcast_live(unsigned long long live0,
                                                         unsigned long long live1, int w) {
  union { unsigned long long u; uint2 v; } t;
  t.u = (w < 64) ? live0 : live1;
  const int src = w & 63;
  const unsigned lo = __shfl(t.v.x, src);
  const unsigned hi = __shfl(t.v.y, src);
  return ((unsigned long long)hi << 32) | lo;
}

__global__ __launch_bounds__(64) void nms_scan(const float4* __restrict__ sbox,
                                               const float* __restrict__ sscore,
                                               const int* __restrict__ slab,
                                               const int* __restrict__ vcount,
                                               const unsigned long long* __restrict__ mask,
                                               float* __restrict__ out) {
  const int lane = threadIdx.x;
  const int V = min(*vcount, NCAND);
  const int nw = (V + 63) >> 6;
  unsigned long long live0 = ~0ULL, live1 = ~0ULL;
  int nk = 0;
  for (int w = 0; w < nw && nk < 100; ++w) {
    const int nb = V - (w << 6);
    const unsigned long long vmask = (nb >= 64) ? ~0ULL : ((1ULL << nb) - 1ULL);
    unsigned long long wv = bcast_live(live0, live1, w) & vmask;
    while (wv && nk < 100) {
      const int b = __ffsll((long long)wv) - 1;
      const int i = (w << 6) + b;
      if (lane == 0) {
        const float4 bb = sbox[i];
        out[nk*4+0] = bb.x; out[nk*4+1] = bb.y; out[nk*4+2] = bb.z; out[nk*4+3] = bb.w;
        out[400 + nk] = (float)slab[i];
        out[500 + nk] = sscore[i];
      }
      const unsigned long long* mrow = mask + (size_t)i * NW;
      if (lane < nw) live0 &= ~mrow[lane];
      if (64 + lane < nw) live1 &= ~mrow[64 + lane];
      nk++;
      wv = bcast_live(live0, live1, w) & vmask;
      wv &= (b == 63) ? 0ULL : ~((2ULL << b) - 1ULL);
    }
  }
  for (int r = nk + lane; r < 100; r += 64) {
    out[r*4+0] = 0.0f; out[r*4+1] = 0.0f; out[r*4+2] = 0.0f; out[r*4+3] = 0.0f;
    out[400 + r] = -1.0f;
    out[500 + r] = 0.0f;
  }
}

// ---------------- launch ----------------
extern "C" void kernel_launch(void* const* d_in, const int* in_sizes, int n_in,
                              void* d_out, int out_size, void* d_ws, size_t ws_size,
                              hipStream_t stream) {
  const float* feat   = (const float*)d_in[1];
  const float* props  = (const float*)d_in[2];
  const float* fc6_w  = (const float*)d_in[3];
  const float* fc6_b  = (const float*)d_in[4];
  const float* fc7_w  = (const float*)d_in[5];
  const float* fc7_b  = (const float*)d_in[6];
  const float* cls_w  = (const float*)d_in[7];
  const float* cls_b  = (const float*)d_in[8];
  const float* reg_w  = (const float*)d_in[9];
  const float* reg_b  = (const float*)d_in[10];

  char* ws = (char*)d_ws;
  // region1: X (30.1 MB) then reused as Pt (up to 34.4 MB)
  const size_t XSZ = (size_t)P_N * FIN * 2;
  const size_t R1  = (size_t)KS6 * P_N * D_N * 4;
  _Float16* Xhi = (_Float16*)ws;
  _Float16* Xlo = (_Float16*)(ws + XSZ);
  float*    Pt  = (float*)ws;
  // region2: ft (6.9 MB) then reused as X' blob (38.5 MB)
  char* reg2 = ws + R1;
  float* ft   = (float*)reg2;
  char*  Xb   = reg2;
  const size_t XBSZ = (size_t)3 * 784 * 16384;
  // region3
  size_t off = R1 + XBSZ;
  auto alloc = [&](size_t bytes) -> void* {
    void* p = ws + off;
    off += (bytes + 255) & ~(size_t)255;
    return p;
  };
  char*  h6b   = (char*)alloc((size_t)3 * 32 * 16384);
  char*  h7b   = (char*)alloc((size_t)3 * 32 * 16384);
  float* Wpad  = (float*)alloc((size_t)NHEAD * D_N * 4);
  float* bpad  = (float*)alloc((size_t)NHEAD * 4);
  float* cboxes= (float*)alloc((size_t)NCAND * 4 * 4);
  unsigned long long* ckeys = (unsigned long long*)alloc((size_t)NCAND * 8);
  float4* sbox = (float4*)alloc((size_t)NCAND * 16);
  float* sscore= (float*)alloc((size_t)NCAND * 4);
  int*   slab  = (int*)alloc((size_t)NCAND * 4);
  unsigned long long* supmask = (unsigned long long*)alloc((size_t)NCAND * NW * 8);
  int*   vcount= (int*)alloc(256);
  (void)ws_size; (void)in_sizes; (void)n_in; (void)out_size;

  // 0) fused: feat transpose + head-weight padding + vcount zero
  prep_transpose<<<TBLK + NHEAD, 256, 0, stream>>>(feat, ft, cls_w, cls_b, reg_w, reg_b,
                                                   Wpad, bpad, vcount);
  // 1) ROI align -> X hi/lo linear
  roi_align_k<<<dim3(P_N, 2), 256, 0, stream>>>(ft, props, Xhi, Xlo);
  // 2) reshuffle X -> fragment blobs
  reshuffle_x<<<dim3(3, 784), 256, 0, stream>>>(Xhi, Xlo, Xb, P_N, FIN);
  // 3) fc6
  gemm_f16_3p<<<dim3(3, 8, KS6), 256, 0, stream>>>(Xb, fc6_w, Pt, P_N, FIN, STEPS6_PER_Z, D_N);
  reduce_frag<<<150, 256, 0, stream>>>(Pt, fc6_b, h6b, KS6, 32);
  // 4) fc7
  gemm_f16_3p<<<dim3(3, 8, KS7), 256, 0, stream>>>(h6b, fc7_w, Pt, P_N, D_N, STEPS7_PER_Z, D_N);
  reduce_frag<<<150, 256, 0, stream>>>(Pt, fc7_b, h7b, KS7, 32);
  // 5) head GEMM (N=128 padded); logits reduce fused into decode
  gemm_f16_3p<<<dim3(3, 1, KSH), 256, 0, stream>>>(h7b, Wpad, Pt, P_N, D_N, STEPSH_PER_Z, NHEAD);
  // 6) decode (fused logits reduce) + compact
  decode_kernel<<<P_N, 64, 0, stream>>>(Pt, bpad, props, cboxes, ckeys, vcount);
  // 7) sort -> gather
  sort_gather<<<1, 1024, 0, stream>>>(ckeys, vcount, cboxes, sbox, sscore, slab);
  // 8) suppression matrix + single-wave NMS bit-scan
  iou_matrix<<<(NCAND + 3) / 4, 256, 0, stream>>>(sbox, slab, vcount, supmask);
  nms_scan<<<1, 64, 0, stream>>>(sbox, sscore, slab, vcount, supmask, (float*)d_out);
}

// Round 16
// 334.956 us; speedup vs baseline: 1.0763x; 1.0763x over previous
//
#include <hip/hip_runtime.h>
#include <hip/hip_bf16.h>
#include <math.h>

// ---------------- problem constants ----------------
#define P_N   300
#define C_N   512
#define H_F   50
#define W_F   67
#define HW_F  3350
#define D_N   1024
#define FIN   25088
#define NCLS  21
#define NCAND 6000
#define W_IMG 1072.0f
#define H_IMG 800.0f
#define BBOX_CLIP_F 4.135166556742356f
#define KS6   28
#define STEPS6_PER_Z 28
#define KS7   16
#define STEPS7_PER_Z 2
#define KSH   16
#define STEPSH_PER_Z 2
#define NHEAD 128
#define NW    96
#define A_SCALE 16.0f
#define B_SCALE 256.0f
#define O_SCALE (1.0f / 4096.0f)
#define TBLK  1680

typedef __attribute__((ext_vector_type(8)))  _Float16 half8;
typedef __attribute__((ext_vector_type(16))) float    f32x16;

__device__ __forceinline__ void splitA(float f, _Float16& h, _Float16& l) {
  float fs = f * A_SCALE;
  h = (_Float16)fs;
  l = (_Float16)(fs - (float)h);
}

__device__ __forceinline__ int swz(int slot, int ks) {
  return slot ^ ((slot >> 5) & 1) ^ (((slot >> 3) & 1) << 1) ^ ((ks & 1) << 2);
}

// half-index (within the 4096-half hi or lo half-blob) for the 8-half group (row, j8)
__device__ __forceinline__ int blob_half_idx(int row, int j8) {
  const int ksW = j8 >> 1, kc8 = j8 & 1;
  const int mf = row >> 5;
  return (mf * 2 + ksW) * 512 + swz((kc8 << 5) | (row & 31), ksW) * 8;
}

// ---------------- fused: feat transpose + head-weight padding + vcount zero ----------------
__global__ __launch_bounds__(256) void prep_transpose(const float* __restrict__ feat,
                                                      float* __restrict__ ft,
                                                      const float* __restrict__ cls_w,
                                                      const float* __restrict__ cls_b,
                                                      const float* __restrict__ reg_w,
                                                      const float* __restrict__ reg_b,
                                                      float* __restrict__ Wpad,
                                                      float* __restrict__ bpad,
                                                      int* __restrict__ vcount) {
  __shared__ float tile[32][33];
  const int bid = blockIdx.x;
  const int tid = threadIdx.x;
  if (bid < TBLK) {
    const int bx = bid % 105, byy = bid / 105;
    const int s0 = bx * 32, c0 = byy * 32;
    const int tx = tid & 31, ty = tid >> 5;
    for (int r = ty; r < 32; r += 8) {
      int c = c0 + r, s = s0 + tx;
      tile[r][tx] = (s < HW_F) ? feat[(size_t)c * HW_F + s] : 0.0f;
    }
    __syncthreads();
    for (int r = ty; r < 32; r += 8) {
      int s = s0 + r, c = c0 + tx;
      if (s < HW_F) ft[(size_t)s * C_N + c] = tile[tx][r];
    }
  } else {
    const int row = bid - TBLK;
    if (row == 0 && tid == 0) *vcount = 0;
    const float* src = (row < NCLS) ? (cls_w + (size_t)row * D_N)
                     : (row < 105)  ? (reg_w + (size_t)(row - NCLS) * D_N) : nullptr;
    float4 v = make_float4(0.f, 0.f, 0.f, 0.f);
    if (src) v = reinterpret_cast<const float4*>(src)[tid];
    reinterpret_cast<float4*>(Wpad + (size_t)row * D_N)[tid] = v;
    if (tid == 0)
      bpad[row] = (row < NCLS) ? cls_b[row] : (row < 105) ? reg_b[row - NCLS] : 0.0f;
  }
}

// ---------------- ROI align: block per (proposal, channel-half), branch-free inner loop ----------------
__global__ __launch_bounds__(256, 3) void roi_align_k(const float* __restrict__ ft,
                                                      const float* __restrict__ rois,
                                                      _Float16* __restrict__ Xhi,
                                                      _Float16* __restrict__ Xlo) {
  __shared__ _Float16 hbuf[12544] __attribute__((aligned(16)));
  __shared__ _Float16 lbuf[12544] __attribute__((aligned(16)));
  __shared__ float g_ly[14], g_hy[14], g_lx[14], g_hx[14];
  __shared__ int   g_yoL[14], g_yoH[14], g_xoL[14], g_xoH[14];

  const int p   = blockIdx.x;
  const int ch  = blockIdx.y;
  const int tid = threadIdx.x;

  if (tid < 14) {
    const float rx0 = rois[p*4+0], ry0 = rois[p*4+1], rx1 = rois[p*4+2], ry1 = rois[p*4+3];
    const float x0r = rx0 * 0.0625f - 0.5f;
    const float y0r = ry0 * 0.0625f - 0.5f;
    const float bw  = (rx1 - rx0) * 0.0625f * (1.0f / 7.0f);
    const float bh  = (ry1 - ry0) * 0.0625f * (1.0f / 7.0f);
    const float t   = ((float)tid + 0.5f) * 0.5f;

    const float ys = y0r + bh * t;
    const bool vy = (ys >= -1.0f) && (ys <= (float)H_F);
    float y = fminf(fmaxf(ys, 0.0f), (float)(H_F - 1));
    int yi = (int)floorf(y);
    const int yh = min(yi + 1, H_F - 1);
    float ly = y - (float)yi, hy = 1.0f - (y - (float)yi);
    if (!vy) { ly = 0.0f; hy = 0.0f; }
    g_ly[tid] = ly; g_hy[tid] = hy;
    g_yoL[tid] = yi * (W_F * C_N); g_yoH[tid] = yh * (W_F * C_N);

    const float xs = x0r + bw * t;
    const bool vx = (xs >= -1.0f) && (xs <= (float)W_F);
    float x = fminf(fmaxf(xs, 0.0f), (float)(W_F - 1));
    int xi = (int)floorf(x);
    const int xh = min(xi + 1, W_F - 1);
    float lx = x - (float)xi, hx = 1.0f - (x - (float)xi);
    if (!vx) { lx = 0.0f; hx = 0.0f; }
    g_lx[tid] = lx; g_hx[tid] = hx;
    g_xoL[tid] = xi * C_N; g_xoH[tid] = xh * C_N;
  }
  __syncthreads();

  const float* ftc = ft + ch * 256 + tid;
#pragma unroll 4
  for (int cell = 0; cell < 49; ++cell) {
    const int py = cell / 7;
    const int px = cell - py * 7;
    float acc = 0.0f;
#pragma unroll
    for (int sy = 0; sy < 2; ++sy) {
      const int iy = 2 * py + sy;
      const float ly = g_ly[iy], hy = g_hy[iy];
      const int yoL = g_yoL[iy], yoH = g_yoH[iy];
#pragma unroll
      for (int sx = 0; sx < 2; ++sx) {
        const int ix = 2 * px + sx;
        const float lx = g_lx[ix], hx = g_hx[ix];
        const int xoL = g_xoL[ix], xoH = g_xoH[ix];
        acc += (hy*hx)*ftc[yoL+xoL] + (hy*lx)*ftc[yoL+xoH]
             + (ly*hx)*ftc[yoH+xoL] + (ly*lx)*ftc[yoH+xoH];
      }
    }
    _Float16 h, l;
    splitA(acc * 0.25f, h, l);
    hbuf[tid * 49 + cell] = h;
    lbuf[tid * 49 + cell] = l;
  }
  __syncthreads();

  const size_t base = (size_t)p * FIN + (size_t)ch * 12544;
  const uint4* hs = (const uint4*)hbuf;
  const uint4* ls = (const uint4*)lbuf;
  uint4* dh = (uint4*)(Xhi + base);
  uint4* dl = (uint4*)(Xlo + base);
  for (int k = tid; k < 1568; k += 256) { dh[k] = hs[k]; dl[k] = ls[k]; }
}

// ---------------- reshuffle: linear hi/lo rows -> per-(tile,step) 16KB fragment blobs ----------------
__global__ __launch_bounds__(256) void reshuffle_x(const _Float16* __restrict__ Shi,
                                                   const _Float16* __restrict__ Slo,
                                                   char* __restrict__ blob,
                                                   int M2, int K) {
  __shared__ _Float16 buf[8192] __attribute__((aligned(16)));
  const int tile = blockIdx.x, step = blockIdx.y;
  const int tid = threadIdx.x;
  const int steps = K >> 5;
#pragma unroll
  for (int i = 0; i < 4; ++i) {
    const int g = tid + i * 256;            // 0..1023
    const int half = g >> 9;                // 0: hi, 1: lo
    const int row = (g >> 2) & 127;
    const int j8 = g & 3;
    const int gm = tile * 128 + row;
    uint4 v = make_uint4(0, 0, 0, 0);
    if (gm < M2) {
      const _Float16* src = (half ? Slo : Shi) + (size_t)gm * K + (step << 5) + (j8 << 3);
      v = *reinterpret_cast<const uint4*>(src);
    }
    *reinterpret_cast<uint4*>(buf + half * 4096 + blob_half_idx(row, j8)) = v;
  }
  __syncthreads();
  uint4* dst = (uint4*)(blob + (((size_t)tile * steps + step) << 14));
  const uint4* s = (const uint4*)buf;
#pragma unroll
  for (int i = 0; i < 4; ++i) dst[tid + i * 256] = s[tid + i * 256];
}

// ---------------- MFMA f16 3-product GEMM: A via global_load_lds from fragment blobs (R11 exact) ----
__global__ __launch_bounds__(256, 3) void gemm_f16_3p(
    const char* __restrict__ Ablob, const float* __restrict__ Wt, float* __restrict__ Pt,
    int M, int K, int steps_per_z, int ldc)
{
  __shared__ _Float16 lds[16384] __attribute__((aligned(16)));
  const int tid  = threadIdx.x;
  const int lane = tid & 63, wave = tid >> 6;
  const int wm = wave >> 1, wn = wave & 1;

  // XCD-aware bijective swizzle (grid divisible by 8)
  const int GX = gridDim.x, GY = gridDim.y;
  const int T  = GX * GY * gridDim.z;
  int flat = blockIdx.x + GX * (blockIdx.y + GY * blockIdx.z);
  if ((T & 7) == 0) flat = (flat & 7) * (T >> 3) + (flat >> 3);
  const int bx = flat % GX;
  const int by = (flat / GX) % GY;
  const int bz = flat / (GX * GY);

  const int m0 = bx * 128, n0 = by * 128;
  const int steps_total = K >> 5;
  const int s0 = bz * steps_per_z;
  const int s1 = min(s0 + steps_per_z, steps_total);

  f32x16 acc[2][2];
#pragma unroll
  for (int a = 0; a < 2; ++a)
#pragma unroll
    for (int b = 0; b < 2; ++b)
#pragma unroll
      for (int r = 0; r < 16; ++r) acc[a][b][r] = 0.f;

  const int srow = tid >> 2;
  const int j8   = tid & 3;
  const int ksW  = j8 >> 1, kc8 = j8 & 1;
  const int wslot = swz((kc8 << 5) | (srow & 31), ksW);

  for (int step = s0; step < s1; ++step) {
    const int kb = step << 5;
    // ---- stage A: 4 async global_load_lds per wave (16KB blob -> LDS bytes [0,16384)) ----
    const char* Ab = Ablob + (((size_t)bx * steps_total + step) << 14);
#pragma unroll
    for (int c2 = 0; c2 < 4; ++c2) {
      const int off = ((wave << 2) + c2) << 10;
      __builtin_amdgcn_global_load_lds(
          (const __attribute__((address_space(1))) uint32_t*)(Ab + off + (lane << 4)),
          (__attribute__((address_space(3))) uint32_t*)((char*)lds + off),
          16, 0, 0);
    }
    // ---- stage B (convert f32 W -> f16 hi/lo): 128 rows, 2 chunks per thread ----
#pragma unroll
    for (int half = 0; half < 2; ++half) {
      const int n = srow + half * 64;
      const float* wp = Wt + (size_t)(n0 + n) * K + kb + j8 * 8;
      const float4 f0 = *reinterpret_cast<const float4*>(wp);
      const float4 f1 = *reinterpret_cast<const float4*>(wp + 4);
      float fv[8] = {f0.x, f0.y, f0.z, f0.w, f1.x, f1.y, f1.z, f1.w};
      union { _Float16 h[8]; uint4 v; } uh, ul;
#pragma unroll
      for (int e = 0; e < 8; ++e) {
        float fs = fv[e] * B_SCALE;
        uh.h[e] = (_Float16)fs;
        ul.h[e] = (_Float16)(fs - (float)uh.h[e]);
      }
      const int nf = n >> 5;
      const int base = 8192 + (nf * 2 + ksW) * 512 + wslot * 8;
      *reinterpret_cast<uint4*>(&lds[base])        = uh.v;
      *reinterpret_cast<uint4*>(&lds[4096 + base]) = ul.v;
    }
    __syncthreads();
    // ---- compute: 2 k-halves x 2x2 frags x 3 products ----
#pragma unroll
    for (int ks = 0; ks < 2; ++ks) {
      const int rslot = swz(lane, ks) * 8;
      half8 ah[2], al[2], bh[2], bl[2];
#pragma unroll
      for (int mi = 0; mi < 2; ++mi) {
        const int mf = wm * 2 + mi;
        ah[mi] = *reinterpret_cast<const half8*>(&lds[(mf * 2 + ks) * 512 + rslot]);
        al[mi] = *reinterpret_cast<const half8*>(&lds[4096 + (mf * 2 + ks) * 512 + rslot]);
      }
#pragma unroll
      for (int ni = 0; ni < 2; ++ni) {
        const int nf = wn * 2 + ni;
        bh[ni] = *reinterpret_cast<const half8*>(&lds[8192  + (nf * 2 + ks) * 512 + rslot]);
        bl[ni] = *reinterpret_cast<const half8*>(&lds[12288 + (nf * 2 + ks) * 512 + rslot]);
      }
#pragma unroll
      for (int mi = 0; mi < 2; ++mi)
#pragma unroll
        for (int ni = 0; ni < 2; ++ni) {
          acc[mi][ni] = __builtin_amdgcn_mfma_f32_32x32x16_f16(ah[mi], bh[ni], acc[mi][ni], 0, 0, 0);
          acc[mi][ni] = __builtin_amdgcn_mfma_f32_32x32x16_f16(ah[mi], bl[ni], acc[mi][ni], 0, 0, 0);
          acc[mi][ni] = __builtin_amdgcn_mfma_f32_32x32x16_f16(al[mi], bh[ni], acc[mi][ni], 0, 0, 0);
        }
    }
    __syncthreads();
  }
  const int col = lane & 31, rhi = lane >> 5;
  float* outp = Pt + (size_t)bz * ((size_t)M * ldc);
#pragma unroll
  for (int mi = 0; mi < 2; ++mi)
#pragma unroll
    for (int ni = 0; ni < 2; ++ni) {
      const int n = n0 + (wn * 2 + ni) * 32 + col;
      if (n >= ldc) continue;
#pragma unroll
      for (int r = 0; r < 16; ++r) {
        const int m = m0 + (wm * 2 + mi) * 32 + ((r & 3) + 8 * (r >> 2) + 4 * rhi);
        if (m < M) outp[(size_t)m * ldc + n] = acc[mi][ni][r] * O_SCALE;
      }
    }
}

// ---------------- reduce split-K + bias + relu -> fragment blob (hi/lo), D=1024 ----------------
__global__ __launch_bounds__(256) void reduce_frag(const float* __restrict__ Pt,
                                                   const float* __restrict__ bias,
                                                   char* __restrict__ blob,
                                                   int KS, int stepsB) {
  const int g = blockIdx.x * 256 + threadIdx.x;
  if (g >= P_N * 128) return;
  const int m = g >> 7;
  const int gg = g & 127;
  const int n0 = gg << 3;
  float s[8];
#pragma unroll
  for (int e = 0; e < 8; ++e) s[e] = bias[n0 + e];
  for (int k2 = 0; k2 < KS; ++k2) {
    const float* pp = Pt + ((size_t)k2 * P_N + m) * D_N + n0;
    const float4 a = *reinterpret_cast<const float4*>(pp);
    const float4 b = *reinterpret_cast<const float4*>(pp + 4);
    s[0]+=a.x; s[1]+=a.y; s[2]+=a.z; s[3]+=a.w;
    s[4]+=b.x; s[5]+=b.y; s[6]+=b.z; s[7]+=b.w;
  }
  union { _Float16 h[8]; uint4 v; } uh, ul;
#pragma unroll
  for (int e = 0; e < 8; ++e) {
    float r = fmaxf(s[e], 0.0f);
    _Float16 h, l; splitA(r, h, l);
    uh.h[e] = h; ul.h[e] = l;
  }
  const int tile = m >> 7, row = m & 127;
  const int step = gg >> 2, j8 = gg & 3;
  _Float16* dst = (_Float16*)(blob + (((size_t)tile * stepsB + step) << 14));
  const int hidx = blob_half_idx(row, j8);
  *reinterpret_cast<uint4*>(dst + hidx) = uh.v;
  *reinterpret_cast<uint4*>(dst + 4096 + hidx) = ul.v;
}

// ---------------- decode (fused logits-reduce): softmax + box decode + validity + compact ----------
__global__ __launch_bounds__(64) void decode_kernel(const float* __restrict__ Pt,
                                                    const float* __restrict__ bpad,
                                                    const float* __restrict__ props,
                                                    float* __restrict__ cboxes,
                                                    unsigned long long* __restrict__ ckeys,
                                                    int* __restrict__ vcount) {
  const int p = blockIdx.x;
  const int lane = threadIdx.x;
  __shared__ float lg[NHEAD];

  for (int o = lane; o < NHEAD; o += 64) {
    float s = 0.0f;
    for (int k = 0; k < KSH; ++k)
      s += Pt[((size_t)k * P_N + p) * NHEAD + o];
    lg[o] = s + bpad[o];
  }
  __syncthreads();

  float s = (lane < NCLS) ? lg[lane] : -__builtin_inff();
  float mx = s;
#pragma unroll
  for (int off = 32; off > 0; off >>= 1) mx = fmaxf(mx, __shfl_xor(mx, off));
  float e = (lane < NCLS) ? expf(s - mx) : 0.0f;
  float sum = e;
#pragma unroll
  for (int off = 32; off > 0; off >>= 1) sum += __shfl_xor(sum, off);
  const float sm = e / sum;

  if (lane >= 1 && lane < NCLS) {
    const int c = lane;
    const float x0 = props[p*4+0], y0 = props[p*4+1], x1 = props[p*4+2], y1 = props[p*4+3];
    const float w = x1 - x0, hh = y1 - y0;
    const float cx = x0 + 0.5f * w, cy = y0 + 0.5f * hh;
    const float dx = lg[NCLS + c*4 + 0];
    const float dy = lg[NCLS + c*4 + 1];
    const float dw = fminf(lg[NCLS + c*4 + 2], BBOX_CLIP_F);
    const float dh = fminf(lg[NCLS + c*4 + 3], BBOX_CLIP_F);
    const float pcx = dx * w + cx, pcy = dy * hh + cy;
    const float pw = expf(dw) * w, ph = expf(dh) * hh;
    float bx0 = pcx - 0.5f * pw, by0 = pcy - 0.5f * ph;
    float bx1 = pcx + 0.5f * pw, by1 = pcy + 0.5f * ph;
    bx0 = fminf(fmaxf(bx0, 0.0f), W_IMG);
    by0 = fminf(fmaxf(by0, 0.0f), H_IMG);
    bx1 = fminf(fmaxf(bx1, 0.0f), W_IMG);
    by1 = fminf(fmaxf(by1, 0.0f), H_IMG);
    const int idx = p * 20 + (c - 1);
    cboxes[idx*4+0] = bx0; cboxes[idx*4+1] = by0;
    cboxes[idx*4+2] = bx1; cboxes[idx*4+3] = by1;
    const bool valid = (sm > 0.05f) && ((bx1 - bx0) >= 1.0f) && ((by1 - by0) >= 1.0f);
    if (valid) {
      int pos = atomicAdd(vcount, 1);
      unsigned u = __float_as_uint(sm);
      ckeys[pos] = ((unsigned long long)(~u) << 32) | (unsigned)idx;
    }
  }
}

// ---------------- bitonic sort + gather ----------------
__global__ __launch_bounds__(1024) void sort_gather(const unsigned long long* __restrict__ ckeys,
                                                    const int* __restrict__ vcount,
                                                    const float* __restrict__ cboxes,
                                                    float4* __restrict__ sbox,
                                                    float* __restrict__ sscore,
                                                    int* __restrict__ slab) {
  __shared__ unsigned long long keys[8192];
  const int tid = threadIdx.x;
  const int V = *vcount;
  int Npad = 64; while (Npad < V) Npad <<= 1;
  for (int i = tid; i < Npad; i += 1024)
    keys[i] = (i < V) ? ckeys[i] : ~0ULL;
  __syncthreads();
  for (int kk = 2; kk <= Npad; kk <<= 1) {
    for (int j = kk >> 1; j > 0; j >>= 1) {
      for (int i = tid; i < Npad; i += 1024) {
        int ij = i ^ j;
        if (ij > i) {
          unsigned long long a = keys[i], b = keys[ij];
          bool up = ((i & kk) == 0);
          if ((a > b) == up) { keys[i] = b; keys[ij] = a; }
        }
      }
      __syncthreads();
    }
  }
  for (int i = tid; i < V; i += 1024) {
    unsigned long long key = keys[i];
    int idx = (int)(key & 0xffffffffu);
    sbox[i]   = *reinterpret_cast<const float4*>(&cboxes[(size_t)idx * 4]);
    sscore[i] = __uint_as_float(~(unsigned)(key >> 32));
    slab[i]   = idx % 20;
  }
}

// ---------------- suppression matrix ----------------
__global__ __launch_bounds__(256) void iou_matrix(const float4* __restrict__ sbox,
                                                  const int* __restrict__ slab,
                                                  const int* __restrict__ vcount,
                                                  unsigned long long* __restrict__ mask) {
  const int V = *vcount;
  const int i = blockIdx.x * 4 + (threadIdx.x >> 6);
  const int lane = threadIdx.x & 63;
  if (i >= V) return;
  const float4 bi = sbox[i];
  const int li = slab[i];
  const float ai = (bi.z - bi.x) * (bi.w - bi.y);
  const int nw = (V + 63) >> 6;
  for (int w = 0; w < nw; ++w) {
    const int j = (w << 6) + lane;
    bool sup = false;
    if (j > i && j < V && slab[j] == li) {
      const float4 bj = sbox[j];
      const float iw = fminf(bi.z, bj.z) - fmaxf(bi.x, bj.x);
      const float ih = fminf(bi.w, bj.w) - fmaxf(bi.y, bj.y);
      const float inter = fmaxf(iw, 0.0f) * fmaxf(ih, 0.0f);
      const float aj = (bj.z - bj.x) * (bj.w - bj.y);
      sup = inter / (ai + aj - inter) > 0.5f;
    }
    const unsigned long long m = __ballot(sup);
    if (lane == 0) mask[(size_t)i * NW + w] = m;
  }
}

// ---------------- NMS scan ----------------
__device__ __forceinline__ unsigned long long bcast_live(unsigned long long live0,
                                                         unsigned long long live1, int w) {
  union { unsigned long long u; uint2 v; } t;
  t.u = (w < 64) ? live0 : live1;
  const int src = w & 63;
  const unsigned lo = __shfl(t.v.x, src);
  const unsigned hi = __shfl(t.v.y, src);
  return ((unsigned long long)hi << 32) | lo;
}

__global__ __launch_bounds__(64) void nms_scan(const float4* __restrict__ sbox,
                                               const float* __restrict__ sscore,
                                               const int* __restrict__ slab,
                                               const int* __restrict__ vcount,
                                               const unsigned long long* __restrict__ mask,
                                               float* __restrict__ out) {
  const int lane = threadIdx.x;
  const int V = min(*vcount, NCAND);
  const int nw = (V + 63) >> 6;
  unsigned long long live0 = ~0ULL, live1 = ~0ULL;
  int nk = 0;
  for (int w = 0; w < nw && nk < 100; ++w) {
    const int nb = V - (w << 6);
    const unsigned long long vmask = (nb >= 64) ? ~0ULL : ((1ULL << nb) - 1ULL);
    unsigned long long wv = bcast_live(live0, live1, w) & vmask;
    while (wv && nk < 100) {
      const int b = __ffsll((long long)wv) - 1;
      const int i = (w << 6) + b;
      if (lane == 0) {
        const float4 bb = sbox[i];
        out[nk*4+0] = bb.x; out[nk*4+1] = bb.y; out[nk*4+2] = bb.z; out[nk*4+3] = bb.w;
        out[400 + nk] = (float)slab[i];
        out[500 + nk] = sscore[i];
      }
      const unsigned long long* mrow = mask + (size_t)i * NW;
      if (lane < nw) live0 &= ~mrow[lane];
      if (64 + lane < nw) live1 &= ~mrow[64 + lane];
      nk++;
      wv = bcast_live(live0, live1, w) & vmask;
      wv &= (b == 63) ? 0ULL : ~((2ULL << b) - 1ULL);
    }
  }
  for (int r = nk + lane; r < 100; r += 64) {
    out[r*4+0] = 0.0f; out[r*4+1] = 0.0f; out[r*4+2] = 0.0f; out[r*4+3] = 0.0f;
    out[400 + r] = -1.0f;
    out[500 + r] = 0.0f;
  }
}

// ---------------- launch ----------------
extern "C" void kernel_launch(void* const* d_in, const int* in_sizes, int n_in,
                              void* d_out, int out_size, void* d_ws, size_t ws_size,
                              hipStream_t stream) {
  const float* feat   = (const float*)d_in[1];
  const float* props  = (const float*)d_in[2];
  const float* fc6_w  = (const float*)d_in[3];
  const float* fc6_b  = (const float*)d_in[4];
  const float* fc7_w  = (const float*)d_in[5];
  const float* fc7_b  = (const float*)d_in[6];
  const float* cls_w  = (const float*)d_in[7];
  const float* cls_b  = (const float*)d_in[8];
  const float* reg_w  = (const float*)d_in[9];
  const float* reg_b  = (const float*)d_in[10];

  char* ws = (char*)d_ws;
  // region1: X (30.1 MB) then reused as Pt (up to 34.4 MB)
  const size_t XSZ = (size_t)P_N * FIN * 2;
  const size_t R1  = (size_t)KS6 * P_N * D_N * 4;
  _Float16* Xhi = (_Float16*)ws;
  _Float16* Xlo = (_Float16*)(ws + XSZ);
  float*    Pt  = (float*)ws;
  // region2: ft (6.9 MB) then reused as X' blob (38.5 MB)
  char* reg2 = ws + R1;
  float* ft   = (float*)reg2;
  char*  Xb   = reg2;
  const size_t XBSZ = (size_t)3 * 784 * 16384;
  // region3
  size_t off = R1 + XBSZ;
  auto alloc = [&](size_t bytes) -> void* {
    void* p = ws + off;
    off += (bytes + 255) & ~(size_t)255;
    return p;
  };
  char*  h6b   = (char*)alloc((size_t)3 * 32 * 16384);
  char*  h7b   = (char*)alloc((size_t)3 * 32 * 16384);
  float* Wpad  = (float*)alloc((size_t)NHEAD * D_N * 4);
  float* bpad  = (float*)alloc((size_t)NHEAD * 4);
  float* cboxes= (float*)alloc((size_t)NCAND * 4 * 4);
  unsigned long long* ckeys = (unsigned long long*)alloc((size_t)NCAND * 8);
  float4* sbox = (float4*)alloc((size_t)NCAND * 16);
  float* sscore= (float*)alloc((size_t)NCAND * 4);
  int*   slab  = (int*)alloc((size_t)NCAND * 4);
  unsigned long long* supmask = (unsigned long long*)alloc((size_t)NCAND * NW * 8);
  int*   vcount= (int*)alloc(256);
  (void)ws_size; (void)in_sizes; (void)n_in; (void)out_size;

  // 0) fused: feat transpose + head-weight padding + vcount zero
  prep_transpose<<<TBLK + NHEAD, 256, 0, stream>>>(feat, ft, cls_w, cls_b, reg_w, reg_b,
                                                   Wpad, bpad, vcount);
  // 1) ROI align -> X hi/lo linear
  roi_align_k<<<dim3(P_N, 2), 256, 0, stream>>>(ft, props, Xhi, Xlo);
  // 2) reshuffle X -> fragment blobs
  reshuffle_x<<<dim3(3, 784), 256, 0, stream>>>(Xhi, Xlo, Xb, P_N, FIN);
  // 3) fc6
  gemm_f16_3p<<<dim3(3, 8, KS6), 256, 0, stream>>>(Xb, fc6_w, Pt, P_N, FIN, STEPS6_PER_Z, D_N);
  reduce_frag<<<150, 256, 0, stream>>>(Pt, fc6_b, h6b, KS6, 32);
  // 4) fc7
  gemm_f16_3p<<<dim3(3, 8, KS7), 256, 0, stream>>>(h6b, fc7_w, Pt, P_N, D_N, STEPS7_PER_Z, D_N);
  reduce_frag<<<150, 256, 0, stream>>>(Pt, fc7_b, h7b, KS7, 32);
  // 5) head GEMM (N=128 padded); logits reduce fused into decode
  gemm_f16_3p<<<dim3(3, 1, KSH), 256, 0, stream>>>(h7b, Wpad, Pt, P_N, D_N, STEPSH_PER_Z, NHEAD);
  // 6) decode (fused logits reduce) + compact
  decode_kernel<<<P_N, 64, 0, stream>>>(Pt, bpad, props, cboxes, ckeys, vcount);
  // 7) sort -> gather
  sort_gather<<<1, 1024, 0, stream>>>(ckeys, vcount, cboxes, sbox, sscore, slab);
  // 8) suppression matrix + single-wave NMS bit-scan
  iou_matrix<<<(NCAND + 3) / 4, 256, 0, stream>>>(sbox, slab, vcount, supmask);
  nms_scan<<<1, 64, 0, stream>>>(sbox, sscore, slab, vcount, supmask, (float*)d_out);
}